// Round 14
// baseline (552.611 us; speedup 1.0000x reference)
//
#include <hip/hip_runtime.h>
#include <math.h>

#define N_NODES  50000
#define N_EDGES  800000
#define HIDDEN   128
#define N_LAYERS 3
#define N_MASKED 25000
#define N_GRAPHS 64
#define SLICE_STRIDE ((size_t)N_NODES * 16)   // floats per slice in sliced tables

typedef __attribute__((ext_vector_type(8))) short bf16x8;
typedef __attribute__((ext_vector_type(4))) float f32x4;

// ordered float<->uint mapping (monotonic): preserves IEEE total order
__device__ __forceinline__ unsigned fmap(float f) {
    unsigned u = __float_as_uint(f);
    return (u & 0x80000000u) ? ~u : (u | 0x80000000u);
}
__device__ __forceinline__ float funmap(unsigned u) {
    return __uint_as_float((u & 0x80000000u) ? (u & 0x7FFFFFFFu) : ~u);
}

// split f32 -> bf16 hi (RNE) + bf16 lo (RNE of remainder), packed hi | lo<<16
__device__ __forceinline__ unsigned pack_split(float x) {
    unsigned u = __float_as_uint(x);
    unsigned hi = (u + 0x7fffu + ((u >> 16) & 1u)) >> 16;
    float rem = x - __uint_as_float(hi << 16);
    unsigned v = __float_as_uint(rem);
    unsigned lo = (v + 0x7fffu + ((v >> 16) & 1u)) >> 16;
    return hi | (lo << 16);
}

// ---------------- degree count (in-degree via dst) ----------------
__global__ void count_deg_kernel(const int* __restrict__ dst, unsigned* __restrict__ deg) {
    int i = blockIdx.x * blockDim.x + threadIdx.x;
    if (i < N_EDGES) atomicAdd(&deg[dst[i]], 1u);
}

__global__ void dinv_kernel(const unsigned* __restrict__ deg, float* __restrict__ dinv) {
    int i = blockIdx.x * blockDim.x + threadIdx.x;
    if (i < N_NODES) dinv[i] = rsqrtf((float)(deg[i] + 1u));   // +1 self-loop
}

// ---------------- prefix sum: per-block inclusive scan ----------------
__global__ void scan_block_kernel(const unsigned* __restrict__ deg, unsigned* __restrict__ incl,
                                  unsigned* __restrict__ bsum) {
    __shared__ unsigned s[1024];
    int i = blockIdx.x * 1024 + threadIdx.x;
    unsigned v = (i < N_NODES) ? deg[i] : 0u;
    s[threadIdx.x] = v;
    __syncthreads();
    for (int off = 1; off < 1024; off <<= 1) {
        unsigned t = (threadIdx.x >= off) ? s[threadIdx.x - off] : 0u;
        __syncthreads();
        s[threadIdx.x] += t;
        __syncthreads();
    }
    if (i < N_NODES) incl[i] = s[threadIdx.x];
    if (threadIdx.x == 1023) bsum[blockIdx.x] = s[1023];
}

__global__ void scan_bsum_kernel(unsigned* __restrict__ bsum, int n) {
    if (blockIdx.x == 0 && threadIdx.x == 0) {
        unsigned run = 0;
        for (int i = 0; i < n; ++i) { unsigned t = bsum[i]; bsum[i] = run; run += t; }
    }
}

__global__ void scan_finalize_kernel(const unsigned* __restrict__ incl,
                                     const unsigned* __restrict__ bsum_ex,
                                     unsigned* __restrict__ row_ptr,
                                     unsigned* __restrict__ cursor) {
    int i = blockIdx.x * blockDim.x + threadIdx.x;
    if (i <= N_NODES) {
        unsigned v = (i == 0) ? 0u : incl[i - 1] + bsum_ex[(i - 1) >> 10];
        row_ptr[i] = v;
        if (i < N_NODES) cursor[i] = v;
    }
}

// ---------------- CSR fill ----------------
__global__ void fill_csr_kernel(const int* __restrict__ src, const int* __restrict__ dst,
                                unsigned* __restrict__ cursor, int* __restrict__ csr_src) {
    int e = blockIdx.x * blockDim.x + threadIdx.x;
    if (e < N_EDGES) {
        unsigned p = atomicAdd(&cursor[dst[e]], 1u);
        csr_src[p] = src[e];
    }
}

// ---------------- W repack into MFMA B-fragment order + hi/lo split ----------------
__global__ void wprep_kernel(const float* __restrict__ W,
                             unsigned short* __restrict__ Whi,
                             unsigned short* __restrict__ Wlo) {
    int idx = blockIdx.x * 256 + threadIdx.x;
    if (idx >= 3 * 16384) return;
    int j     = idx & 7;
    int lane  = (idx >> 3) & 63;
    int ct    = (idx >> 9) & 7;
    int ks    = (idx >> 12) & 3;
    int layer = idx >> 14;
    int k = ks * 32 + (lane >> 4) * 8 + j;
    int n = ct * 16 + (lane & 15);
    unsigned p = pack_split(W[layer * 16384 + k * 128 + n]);
    Whi[idx] = (unsigned short)(p & 0xffffu);
    Wlo[idx] = (unsigned short)(p >> 16);
}

// ---------------- x -> packed split-bf16 ----------------
__global__ void xpack_kernel(const float* __restrict__ x, unsigned* __restrict__ xp, int n) {
    int i = blockIdx.x * 256 + threadIdx.x;
    if (i < n) xp[i] = pack_split(x[i]);
}

// ---------------- MFMA GEMM: C[nrows x 128] = unpack(Ap) @ W, templated epilogue ----
// MODE 0: OutS[slice][r][16] = dinv[r] * C[r]               (sliced f32 table out)
// MODE 1: OutS[slice][r][16] = dinv[r] * ELU(C[r] + bias)   (sliced f32 table out)
// MODE 2: atomicMax(gmax[batch[r]], fmap(ELU(C[r] + bias)))
template<int MODE>
__global__ __launch_bounds__(256, 2) void mfma_gemm_kernel(const unsigned* __restrict__ Ap,
                                                           const unsigned short* __restrict__ Wh,
                                                           const unsigned short* __restrict__ Wl,
                                                           const float* __restrict__ dinv,
                                                           const float* __restrict__ bias,
                                                           const int* __restrict__ batch,
                                                           unsigned* __restrict__ gmax,
                                                           float* __restrict__ OutS,
                                                           int nrows) {
    __shared__ __align__(16) unsigned short WhL[16384];   // 32 KB
    __shared__ __align__(16) unsigned short WlL[16384];   // 32 KB
    const int tid = threadIdx.x;
    const int lane = tid & 63;
    const int wv = tid >> 6;
    const int rowBase = blockIdx.x * 64 + wv * 16;
    const bool active = rowBase < nrows;

    int arow = rowBase + (lane & 15);
    if (arow > nrows - 1) arow = nrows - 1;
    const unsigned* aptr = Ap + (size_t)arow * 128 + (lane >> 4) * 8;
    uint4 pa[8];
    #pragma unroll
    for (int q = 0; q < 8; ++q)
        pa[q] = active ? *(const uint4*)(aptr + (q >> 1) * 32 + (q & 1) * 4)
                       : make_uint4(0, 0, 0, 0);

    {
        const uint4* gh = (const uint4*)Wh;
        const uint4* gl = (const uint4*)Wl;
        uint4* sh = (uint4*)WhL;
        uint4* sl = (uint4*)WlL;
        #pragma unroll
        for (int i = 0; i < 8; ++i) {
            sh[tid + i * 256] = gh[tid + i * 256];
            sl[tid + i * 256] = gl[tid + i * 256];
        }
    }
    __syncthreads();
    if (!active) return;

    f32x4 acc[8];
    #pragma unroll
    for (int c = 0; c < 8; ++c) acc[c] = (f32x4){0.f, 0.f, 0.f, 0.f};

    #pragma unroll
    for (int ks = 0; ks < 4; ++ks) {
        unsigned pv[8] = {pa[2*ks].x, pa[2*ks].y, pa[2*ks].z, pa[2*ks].w,
                          pa[2*ks+1].x, pa[2*ks+1].y, pa[2*ks+1].z, pa[2*ks+1].w};
        bf16x8 ah, al;
        #pragma unroll
        for (int j = 0; j < 8; ++j) {
            ah[j] = (short)(pv[j] & 0xffffu);
            al[j] = (short)(pv[j] >> 16);
        }
        const unsigned short* wbh = WhL + ks * 4096 + lane * 8;
        const unsigned short* wbl = WlL + ks * 4096 + lane * 8;
        #pragma unroll
        for (int ct = 0; ct < 8; ++ct) {
            bf16x8 bh = *(const bf16x8*)(wbh + ct * 512);
            bf16x8 bl = *(const bf16x8*)(wbl + ct * 512);
            acc[ct] = __builtin_amdgcn_mfma_f32_16x16x32_bf16(ah, bh, acc[ct], 0, 0, 0);
            acc[ct] = __builtin_amdgcn_mfma_f32_16x16x32_bf16(al, bh, acc[ct], 0, 0, 0);
            acc[ct] = __builtin_amdgcn_mfma_f32_16x16x32_bf16(ah, bl, acc[ct], 0, 0, 0);
        }
    }

    // C/D layout: col = lane&15, row = (lane>>4)*4 + reg   [m89-verified]
    const int colBase = lane & 15;
    const int rgrp = lane >> 4;
    #pragma unroll
    for (int r = 0; r < 4; ++r) {
        int row = rowBase + rgrp * 4 + r;
        if (row >= nrows) continue;
        float d = 0.f;
        int bofs = 0;
        if (MODE == 0 || MODE == 1) d = dinv[row];
        if (MODE == 2) bofs = batch[row] * 128;
        #pragma unroll
        for (int ct = 0; ct < 8; ++ct) {
            int col = ct * 16 + colBase;
            float o = acc[ct][r];
            if (MODE == 0) {
                OutS[(size_t)ct * SLICE_STRIDE + (size_t)row * 16 + colBase] = o * d;
            } else {
                o += bias[col];
                o = o > 0.f ? o : expm1f(o);
                if (MODE == 1)
                    OutS[(size_t)ct * SLICE_STRIDE + (size_t)row * 16 + colBase] = o * d;
                else
                    atomicMax(&gmax[bofs + col], fmap(o));
            }
        }
    }
}

// ---------------- XCD-sliced CSR gather v2 ----------------
// slice = blockIdx&7 (XCD-pinned, 3.2 MB table slice/XCD). Wave = one (item, slice).
// Lane -> (edge slot eq = lane>>2, feature quad q = lane&3); each lane loads float4
// => one instr covers 16 edges x 64 B = 1024 B. Tree-reduce over eq; lanes 0-3 write.
// GMODE 0: outS[s][w][16] = dinv_v * ELU(dinv_v * sum + bias)  (sliced f32)
// GMODE 1: outp[w][128]   = pack_split(dinv_v * sum)           (packed row-major)
template<int GMODE>
__global__ __launch_bounds__(256) void gather_kernel(const float* __restrict__ tabS,
                                                     const unsigned* __restrict__ row_ptr,
                                                     const int* __restrict__ csr_src,
                                                     const float* __restrict__ dinv,
                                                     const float* __restrict__ bias,
                                                     float* __restrict__ outS,
                                                     unsigned* __restrict__ outp,
                                                     const int* __restrict__ nodes,
                                                     int n_items) {
    const int b = blockIdx.x;
    const int s = b & 7;
    const int w = (b >> 3) * 4 + (threadIdx.x >> 6);
    if (w >= n_items) return;
    const int lane = threadIdx.x & 63;
    const int eq = lane >> 2;   // edge slot 0..15
    const int q  = lane & 3;    // feature quad 0..3
    const int v = nodes ? nodes[w] : w;

    const float4* __restrict__ tab4 = (const float4*)(tabS + (size_t)s * SLICE_STRIDE);

    const unsigned s0 = row_ptr[v], e0 = row_ptr[v + 1];
    const int cnt = (int)(e0 - s0);

    float4 a = make_float4(0.f, 0.f, 0.f, 0.f);
    if (eq == 0) a = tab4[(size_t)v * 4 + q];   // self-loop row

    for (int i = 0; i < cnt; i += 16) {
        int e = i + eq;
        if (e < cnt) {
            int src = csr_src[s0 + e];
            float4 t = tab4[(size_t)src * 4 + q];
            a.x += t.x; a.y += t.y; a.z += t.z; a.w += t.w;
        }
    }

    // reduce over eq (lanes with same q, stride 4)
    #pragma unroll
    for (int off = 32; off >= 4; off >>= 1) {
        a.x += __shfl_down(a.x, off);
        a.y += __shfl_down(a.y, off);
        a.z += __shfl_down(a.z, off);
        a.w += __shfl_down(a.w, off);
    }

    if (lane < 4) {   // lane == q, holds slice sums for features s*16 + lane*4 .. +3
        float dv = dinv[v];
        if (GMODE == 0) {
            float4 bb = *(const float4*)&bias[s * 16 + lane * 4];
            float4 o;
            o.x = dv * a.x + bb.x; o.y = dv * a.y + bb.y;
            o.z = dv * a.z + bb.z; o.w = dv * a.w + bb.w;
            o.x = o.x > 0.f ? o.x : expm1f(o.x);
            o.y = o.y > 0.f ? o.y : expm1f(o.y);
            o.z = o.z > 0.f ? o.z : expm1f(o.z);
            o.w = o.w > 0.f ? o.w : expm1f(o.w);
            o.x *= dv; o.y *= dv; o.z *= dv; o.w *= dv;   // pre-scale for next gather
            ((float4*)(outS + (size_t)s * SLICE_STRIDE + (size_t)w * 16))[lane] = o;
        } else {
            uint4 pk = make_uint4(pack_split(dv * a.x), pack_split(dv * a.y),
                                  pack_split(dv * a.z), pack_split(dv * a.w));
            ((uint4*)(outp + (size_t)w * 128 + s * 16))[lane] = pk;
        }
    }
}

// ---------------- init gmax to mapped(-inf) ----------------
__global__ void gmax_init_kernel(unsigned* __restrict__ gmax) {
    int i = blockIdx.x * blockDim.x + threadIdx.x;
    if (i < N_GRAPHS * 128) gmax[i] = 0x007FFFFFu;  // fmap(-inf)
}

// ---------------- finish: out[g] = sum_f unmap(gmax[g][f]) * w[f] + b ----------------
__global__ void pool_finish_kernel(const unsigned* __restrict__ gmax,
                                   const float* __restrict__ w, const float* __restrict__ b,
                                   float* __restrict__ out) {
    const int g = blockIdx.x;
    const int f = threadIdx.x;
    float val = funmap(gmax[g * 128 + f]) * w[f];
    #pragma unroll
    for (int off = 32; off > 0; off >>= 1) val += __shfl_down(val, off);
    __shared__ float ps[2];
    if ((threadIdx.x & 63) == 0) ps[threadIdx.x >> 6] = val;
    __syncthreads();
    if (threadIdx.x == 0) out[g] = ps[0] + ps[1] + b[0];
}

extern "C" void kernel_launch(void* const* d_in, const int* in_sizes, int n_in,
                              void* d_out, int out_size, void* d_ws, size_t ws_size,
                              hipStream_t stream) {
    const float* x      = (const float*)d_in[0];
    const int*   ei     = (const int*)d_in[1];
    const int*   mask   = (const int*)d_in[2];
    const int*   batch  = (const int*)d_in[3];
    const float* conv_w = (const float*)d_in[4];
    const float* conv_b = (const float*)d_in[5];
    const float* lt1_w  = (const float*)d_in[6];
    const float* lt1_b  = (const float*)d_in[7];
    float* out = (float*)d_out;

    const int* e_src = ei;
    const int* e_dst = ei + N_EDGES;

    // ---- workspace carve-up (aligned to 256B) ----
    char* ws = (char*)d_ws;
    auto carve = [&](size_t bytes) { char* p = ws; ws += (bytes + 255) & ~(size_t)255; return p; };
    unsigned* deg     = (unsigned*)carve(N_NODES * 4);
    float*    dinv    = (float*)   carve(N_NODES * 4);
    unsigned* row_ptr = (unsigned*)carve((N_NODES + 1) * 4);
    unsigned* cursor  = (unsigned*)carve(N_NODES * 4);
    unsigned* bsum    = (unsigned*)carve(64 * 4);
    unsigned* gmax    = (unsigned*)carve(N_GRAPHS * 128 * 4);
    unsigned short* wph = (unsigned short*)carve(3 * 16384 * 2);
    unsigned short* wpl = (unsigned short*)carve(3 * 16384 * 2);
    int*      csr_src = (int*)     carve((size_t)N_EDGES * 4);
    char*     reg1    = carve((size_t)N_NODES * HIDDEN * 4);   // region 1 (25.6 MB)
    char*     reg2    = carve((size_t)N_NODES * HIDDEN * 4);   // region 2 (25.6 MB)
    unsigned* incl    = (unsigned*)csr_src;  // alias: dead before fill_csr runs

    // region lifetimes:
    //   reg1: xp (packed x) -> bufB (gather0 sliced out) -> bufB2 (GEMM2 sliced out)
    //   reg2: bufA (GEMM1 sliced out) -> bufAp (gather1 packed out) -> bufCp (masked packed out)
    unsigned* xp    = (unsigned*)reg1;
    float*    bufB  = (float*)reg1;
    float*    bufB2 = (float*)reg1;
    float*    bufA  = (float*)reg2;
    unsigned* bufAp = (unsigned*)reg2;
    unsigned* bufCp = (unsigned*)reg2;

    const int NB_SCAN = (N_NODES + 1023) / 1024;  // 49

    // ---- build dinv + CSR + W-prep ----
    hipMemsetAsync(deg, 0, N_NODES * sizeof(unsigned), stream);
    count_deg_kernel<<<(N_EDGES + 255) / 256, 256, 0, stream>>>(e_dst, deg);
    dinv_kernel<<<(N_NODES + 255) / 256, 256, 0, stream>>>(deg, dinv);
    scan_block_kernel<<<NB_SCAN, 1024, 0, stream>>>(deg, incl, bsum);
    scan_bsum_kernel<<<1, 64, 0, stream>>>(bsum, NB_SCAN);
    scan_finalize_kernel<<<(N_NODES + 256) / 256, 256, 0, stream>>>(incl, bsum, row_ptr, cursor);
    fill_csr_kernel<<<(N_EDGES + 255) / 256, 256, 0, stream>>>(e_src, e_dst, cursor, csr_src);
    gmax_init_kernel<<<(N_GRAPHS * 128 + 255) / 256, 256, 0, stream>>>(gmax);
    wprep_kernel<<<(3 * 16384 + 255) / 256, 256, 0, stream>>>(conv_w, wph, wpl);
    xpack_kernel<<<(N_NODES * HIDDEN + 255) / 256, 256, 0, stream>>>(x, xp, N_NODES * HIDDEN);

    const int GEMM_FULL = (N_NODES + 63) / 64;
    const int GEMM_MASK = (N_MASKED + 63) / 64;
    const int GA_FULL_BLK = 8 * ((N_NODES + 3) / 4);
    const int GA_MASK_BLK = 8 * ((N_MASKED + 3) / 4);

    // L1: bufA[sliced] = dinv*(x@W1)
    mfma_gemm_kernel<0><<<GEMM_FULL, 256, 0, stream>>>(xp, wph, wpl, dinv, nullptr,
                                                       nullptr, nullptr, bufA, N_NODES);
    // bufB[sliced] = dinv*ELU(dinv*Agg(bufA) + b1)
    gather_kernel<0><<<GA_FULL_BLK, 256, 0, stream>>>(bufA, row_ptr, csr_src, dinv,
                                                      conv_b, bufB, nullptr, nullptr, N_NODES);
    // L2 gather-first: bufAp[packed] = pack(Agg(bufB))
    gather_kernel<1><<<GA_FULL_BLK, 256, 0, stream>>>(bufB, row_ptr, csr_src, dinv,
                                                      nullptr, nullptr, bufAp, nullptr, N_NODES);
    // bufB2[sliced] = dinv*ELU(bufAp@W2 + b2)
    mfma_gemm_kernel<1><<<GEMM_FULL, 256, 0, stream>>>(bufAp, wph + 16384, wpl + 16384, dinv,
                                                       conv_b + HIDDEN, nullptr, nullptr,
                                                       bufB2, N_NODES);
    // L3 gather-first masked: bufCp[packed] = pack(Agg_mask(bufB2))
    gather_kernel<1><<<GA_MASK_BLK, 256, 0, stream>>>(bufB2, row_ptr, csr_src, dinv,
                                                      nullptr, nullptr, bufCp, mask, N_MASKED);
    // pool(ELU(bufCp@W3 + b3)) via atomicMax
    mfma_gemm_kernel<2><<<GEMM_MASK, 256, 0, stream>>>(bufCp, wph + 32768, wpl + 32768, nullptr,
                                                       conv_b + 2 * HIDDEN, batch, gmax,
                                                       nullptr, N_MASKED);

    pool_finish_kernel<<<N_GRAPHS, HIDDEN, 0, stream>>>(gmax, lt1_w, lt1_b, out);
}

// Round 15
// 393.864 us; speedup vs baseline: 1.4030x; 1.4030x over previous
//
#include <hip/hip_runtime.h>
#include <math.h>

#define N_NODES  50000
#define N_EDGES  800000
#define HIDDEN   128
#define N_LAYERS 3
#define N_MASKED 25000
#define N_GRAPHS 64

typedef __attribute__((ext_vector_type(8))) short bf16x8;
typedef __attribute__((ext_vector_type(4))) float f32x4;

#define GLOAD_LDS16(g, l) \
    __builtin_amdgcn_global_load_lds((const __attribute__((address_space(1))) void*)(g), \
                                     (__attribute__((address_space(3))) void*)(l), 16, 0, 0)

// ordered float<->uint mapping (monotonic): preserves IEEE total order
__device__ __forceinline__ unsigned fmap(float f) {
    unsigned u = __float_as_uint(f);
    return (u & 0x80000000u) ? ~u : (u | 0x80000000u);
}
__device__ __forceinline__ float funmap(unsigned u) {
    return __uint_as_float((u & 0x80000000u) ? (u & 0x7FFFFFFFu) : ~u);
}

// split f32 -> bf16 hi (RNE) + bf16 lo (RNE of remainder), packed hi | lo<<16
__device__ __forceinline__ unsigned pack_split(float x) {
    unsigned u = __float_as_uint(x);
    unsigned hi = (u + 0x7fffu + ((u >> 16) & 1u)) >> 16;
    float rem = x - __uint_as_float(hi << 16);
    unsigned v = __float_as_uint(rem);
    unsigned lo = (v + 0x7fffu + ((v >> 16) & 1u)) >> 16;
    return hi | (lo << 16);
}

// ---------------- degree count (in-degree via dst) ----------------
__global__ void count_deg_kernel(const int* __restrict__ dst, unsigned* __restrict__ deg) {
    int i = blockIdx.x * blockDim.x + threadIdx.x;
    if (i < N_EDGES) atomicAdd(&deg[dst[i]], 1u);
}

__global__ void dinv_kernel(const unsigned* __restrict__ deg, float* __restrict__ dinv) {
    int i = blockIdx.x * blockDim.x + threadIdx.x;
    if (i < N_NODES) dinv[i] = rsqrtf((float)(deg[i] + 1u));   // +1 self-loop
}

// ---------------- prefix sum: per-block inclusive scan ----------------
__global__ void scan_block_kernel(const unsigned* __restrict__ deg, unsigned* __restrict__ incl,
                                  unsigned* __restrict__ bsum) {
    __shared__ unsigned s[1024];
    int i = blockIdx.x * 1024 + threadIdx.x;
    unsigned v = (i < N_NODES) ? deg[i] : 0u;
    s[threadIdx.x] = v;
    __syncthreads();
    for (int off = 1; off < 1024; off <<= 1) {
        unsigned t = (threadIdx.x >= off) ? s[threadIdx.x - off] : 0u;
        __syncthreads();
        s[threadIdx.x] += t;
        __syncthreads();
    }
    if (i < N_NODES) incl[i] = s[threadIdx.x];
    if (threadIdx.x == 1023) bsum[blockIdx.x] = s[1023];
}

__global__ void scan_bsum_kernel(unsigned* __restrict__ bsum, int n) {
    if (blockIdx.x == 0 && threadIdx.x == 0) {
        unsigned run = 0;
        for (int i = 0; i < n; ++i) { unsigned t = bsum[i]; bsum[i] = run; run += t; }
    }
}

__global__ void scan_finalize_kernel(const unsigned* __restrict__ incl,
                                     const unsigned* __restrict__ bsum_ex,
                                     unsigned* __restrict__ row_ptr,
                                     unsigned* __restrict__ cursor) {
    int i = blockIdx.x * blockDim.x + threadIdx.x;
    if (i <= N_NODES) {
        unsigned v = (i == 0) ? 0u : incl[i - 1] + bsum_ex[(i - 1) >> 10];
        row_ptr[i] = v;
        if (i < N_NODES) cursor[i] = v;
    }
}

// ---------------- CSR fill ----------------
__global__ void fill_csr_kernel(const int* __restrict__ src, const int* __restrict__ dst,
                                unsigned* __restrict__ cursor, int* __restrict__ csr_src) {
    int e = blockIdx.x * blockDim.x + threadIdx.x;
    if (e < N_EDGES) {
        unsigned p = atomicAdd(&cursor[dst[e]], 1u);
        csr_src[p] = src[e];
    }
}

// ---------------- W repack into MFMA B-fragment order + hi/lo split ----------------
// ushort idx (per layer): ks*4096 + ct*512 + lane*8 + j; B[k][n], k=ks*32+(lane>>4)*8+j,
// n=ct*16+(lane&15).
__global__ void wprep_kernel(const float* __restrict__ W,
                             unsigned short* __restrict__ Whi,
                             unsigned short* __restrict__ Wlo) {
    int idx = blockIdx.x * 256 + threadIdx.x;
    if (idx >= 3 * 16384) return;
    int j     = idx & 7;
    int lane  = (idx >> 3) & 63;
    int ct    = (idx >> 9) & 7;
    int ks    = (idx >> 12) & 3;
    int layer = idx >> 14;
    int k = ks * 32 + (lane >> 4) * 8 + j;
    int n = ct * 16 + (lane & 15);
    unsigned p = pack_split(W[layer * 16384 + k * 128 + n]);
    Whi[idx] = (unsigned short)(p & 0xffffu);
    Wlo[idx] = (unsigned short)(p >> 16);
}

// ---------------- x -> packed split-bf16 ----------------
__global__ void xpack_kernel(const float* __restrict__ x, unsigned* __restrict__ xp, int n) {
    int i = blockIdx.x * 256 + threadIdx.x;
    if (i < n) xp[i] = pack_split(x[i]);
}

// ---------------- MFMA GEMM v3: all operands via global_load_lds ----------------
// 512 threads = 8 waves, 128 rows/block. LDS 128 KB:
//   [0,64K)   A-tile in fragment order: chunk n = ((w*4+ks)*2+h)*64 + lane,
//             chunk holds uints A[row=blk*128+w*16+(lane&15)][ks*32+(lane>>4)*8+h*4 ..+3]
//   [64K,96K) Wh (prepacked frag order, linear copy)
//   [96K,128K) Wl
// Inner loop: ds_read_b128 (base + lane*16, conflict-free) + 3x MFMA per (ks,ct).
// MODE 0: Out[r] = dinv[r]*C[r];  MODE 1: Out[r] = dinv[r]*ELU(C[r]+bias)
// MODE 2: atomicMax(gmax[batch[r]], fmap(ELU(C[r]+bias)))
template<int MODE>
__global__ __launch_bounds__(512, 2) void mfma_gemm_kernel(const unsigned* __restrict__ Ap,
                                                           const unsigned short* __restrict__ Wh,
                                                           const unsigned short* __restrict__ Wl,
                                                           const float* __restrict__ dinv,
                                                           const float* __restrict__ bias,
                                                           const int* __restrict__ batch,
                                                           unsigned* __restrict__ gmax,
                                                           float* __restrict__ Out,
                                                           int nrows) {
    extern __shared__ char smem[];
    const int tid = threadIdx.x;
    const int lane = tid & 63;
    const int w = tid >> 6;               // wave 0..7
    const int blockRow = blockIdx.x * 128;

    // ---- stage A: 4096 chunks, wave w covers n = w*512 + i*64 + lane ----
    #pragma unroll
    for (int i = 0; i < 8; ++i) {
        int n0 = w * 512 + i * 64;
        int n = n0 + lane;
        int L  = n & 63;
        int h  = (n >> 6) & 1;
        int ks = (n >> 7) & 3;
        int wb = (n >> 9) & 7;
        int row = blockRow + wb * 16 + (L & 15);
        if (row > nrows - 1) row = nrows - 1;
        const unsigned* g = Ap + (size_t)row * 128 + ks * 32 + ((L >> 4) * 8) + h * 4;
        GLOAD_LDS16(g, smem + (size_t)n0 * 16);
    }
    // ---- stage Wh/Wl: 2048 chunks each, linear ----
    #pragma unroll
    for (int i = 0; i < 4; ++i) {
        int m0 = w * 256 + i * 64;
        GLOAD_LDS16((const char*)Wh + (size_t)(m0 + lane) * 16, smem + 65536 + (size_t)m0 * 16);
        GLOAD_LDS16((const char*)Wl + (size_t)(m0 + lane) * 16, smem + 98304 + (size_t)m0 * 16);
    }
    __syncthreads();   // drains vmcnt (global_load_lds) before any ds_read

    if (blockRow + w * 16 >= nrows) return;   // no more barriers below

    f32x4 acc[8];
    #pragma unroll
    for (int c = 0; c < 8; ++c) acc[c] = (f32x4){0.f, 0.f, 0.f, 0.f};

    #pragma unroll
    for (int ks = 0; ks < 4; ++ks) {
        uint4 a0 = *(const uint4*)(smem + (size_t)(((w * 4 + ks) * 2 + 0) * 1024) + lane * 16);
        uint4 a1 = *(const uint4*)(smem + (size_t)(((w * 4 + ks) * 2 + 1) * 1024) + lane * 16);
        unsigned pv[8] = {a0.x, a0.y, a0.z, a0.w, a1.x, a1.y, a1.z, a1.w};
        bf16x8 ah, al;
        #pragma unroll
        for (int j = 0; j < 8; ++j) {
            ah[j] = (short)(pv[j] & 0xffffu);
            al[j] = (short)(pv[j] >> 16);
        }
        const char* wbh = smem + 65536 + ks * 8192 + lane * 16;
        const char* wbl = smem + 98304 + ks * 8192 + lane * 16;
        #pragma unroll
        for (int ct = 0; ct < 8; ++ct) {
            bf16x8 bh = *(const bf16x8*)(wbh + ct * 1024);
            bf16x8 bl = *(const bf16x8*)(wbl + ct * 1024);
            acc[ct] = __builtin_amdgcn_mfma_f32_16x16x32_bf16(ah, bh, acc[ct], 0, 0, 0);
            acc[ct] = __builtin_amdgcn_mfma_f32_16x16x32_bf16(al, bh, acc[ct], 0, 0, 0);
            acc[ct] = __builtin_amdgcn_mfma_f32_16x16x32_bf16(ah, bl, acc[ct], 0, 0, 0);
        }
    }

    // C/D layout: col = lane&15, row = (lane>>4)*4 + reg   [m89-verified]
    const int colBase = lane & 15;
    const int rgrp = lane >> 4;
    #pragma unroll
    for (int r = 0; r < 4; ++r) {
        int row = blockRow + w * 16 + rgrp * 4 + r;
        if (row >= nrows) continue;
        float d = 0.f;
        int bofs = 0;
        if (MODE == 0 || MODE == 1) d = dinv[row];
        if (MODE == 2) bofs = batch[row] * 128;
        #pragma unroll
        for (int ct = 0; ct < 8; ++ct) {
            int col = ct * 16 + colBase;
            float o = acc[ct][r];
            if (MODE == 0) {
                Out[(size_t)row * 128 + col] = o * d;
            } else {
                o += bias[col];
                o = o > 0.f ? o : expm1f(o);
                if (MODE == 1) Out[(size_t)row * 128 + col] = o * d;
                else           atomicMax(&gmax[bofs + col], fmap(o));
            }
        }
    }
}

// ---------------- CSR gather (round-5 shape), templated epilogue ----------------
// sumall = tab[v] + sum_{s in N(v)} tab[s]   (tab rows already carry dinv_s)
// GMODE 0: outf[w] = dinv_v * ELU(dinv_v * sumall + bias)   (f32 table out)
// GMODE 1: outp[w] = pack_split(dinv_v * sumall)            (packed GEMM input out)
template<int GMODE>
__global__ __launch_bounds__(256) void gather_kernel(const float* __restrict__ tab,
                                                     const unsigned* __restrict__ row_ptr,
                                                     const int* __restrict__ csr_src,
                                                     const float* __restrict__ dinv,
                                                     const float* __restrict__ bias,
                                                     float* __restrict__ outf,
                                                     unsigned* __restrict__ outp,
                                                     const int* __restrict__ nodes,
                                                     int n_items) {
    int wid = (blockIdx.x * blockDim.x + threadIdx.x) >> 6;
    int w = wid >> 1;
    if (w >= n_items) return;
    const int f = ((wid & 1) << 6) | (threadIdx.x & 63);
    const int v = nodes ? nodes[w] : w;

    const unsigned s0 = row_ptr[v], e0 = row_ptr[v + 1];
    const float* __restrict__ base = tab + f;

    float acc[8];
    #pragma unroll
    for (int j = 0; j < 8; ++j) acc[j] = 0.f;
    acc[0] = base[(size_t)v << 7];   // self-loop row

    unsigned i = s0;
    if (i + 8 <= e0) {
        int idx[8];
        #pragma unroll
        for (int j = 0; j < 8; ++j) idx[j] = csr_src[i + j];
        for (; i + 16 <= e0; i += 8) {
            int nxt[8];
            #pragma unroll
            for (int j = 0; j < 8; ++j) nxt[j] = csr_src[i + 8 + j];
            #pragma unroll
            for (int j = 0; j < 8; ++j) acc[j] += base[(size_t)idx[j] << 7];
            #pragma unroll
            for (int j = 0; j < 8; ++j) idx[j] = nxt[j];
        }
        #pragma unroll
        for (int j = 0; j < 8; ++j) acc[j] += base[(size_t)idx[j] << 7];
        i += 8;
    }
    if (i + 4 <= e0) {
        #pragma unroll
        for (int j = 0; j < 4; ++j) acc[j] += base[(size_t)csr_src[i + j] << 7];
        i += 4;
    }
    for (; i < e0; ++i) acc[0] += base[(size_t)csr_src[i] << 7];

    float dv = dinv[v];
    float sumall = ((acc[0] + acc[1]) + (acc[2] + acc[3])) +
                   ((acc[4] + acc[5]) + (acc[6] + acc[7]));
    if (GMODE == 0) {
        float o = dv * sumall + bias[f];
        o = o > 0.f ? o : expm1f(o);
        outf[((size_t)w << 7) + f] = o * dv;   // pre-scale for next aggregation
    } else {
        outp[((size_t)w << 7) + f] = pack_split(dv * sumall);
    }
}

// ---------------- init gmax to mapped(-inf) ----------------
__global__ void gmax_init_kernel(unsigned* __restrict__ gmax) {
    int i = blockIdx.x * blockDim.x + threadIdx.x;
    if (i < N_GRAPHS * 128) gmax[i] = 0x007FFFFFu;  // fmap(-inf)
}

// ---------------- finish: out[g] = sum_f unmap(gmax[g][f]) * w[f] + b ----------------
__global__ void pool_finish_kernel(const unsigned* __restrict__ gmax,
                                   const float* __restrict__ w, const float* __restrict__ b,
                                   float* __restrict__ out) {
    const int g = blockIdx.x;
    const int f = threadIdx.x;
    float val = funmap(gmax[g * 128 + f]) * w[f];
    #pragma unroll
    for (int off = 32; off > 0; off >>= 1) val += __shfl_down(val, off);
    __shared__ float ps[2];
    if ((threadIdx.x & 63) == 0) ps[threadIdx.x >> 6] = val;
    __syncthreads();
    if (threadIdx.x == 0) out[g] = ps[0] + ps[1] + b[0];
}

extern "C" void kernel_launch(void* const* d_in, const int* in_sizes, int n_in,
                              void* d_out, int out_size, void* d_ws, size_t ws_size,
                              hipStream_t stream) {
    const float* x      = (const float*)d_in[0];
    const int*   ei     = (const int*)d_in[1];
    const int*   mask   = (const int*)d_in[2];
    const int*   batch  = (const int*)d_in[3];
    const float* conv_w = (const float*)d_in[4];
    const float* conv_b = (const float*)d_in[5];
    const float* lt1_w  = (const float*)d_in[6];
    const float* lt1_b  = (const float*)d_in[7];
    float* out = (float*)d_out;

    const int* e_src = ei;
    const int* e_dst = ei + N_EDGES;

    // ---- workspace carve-up (aligned to 256B) ----
    char* ws = (char*)d_ws;
    auto carve = [&](size_t bytes) { char* p = ws; ws += (bytes + 255) & ~(size_t)255; return p; };
    unsigned* deg     = (unsigned*)carve(N_NODES * 4);
    float*    dinv    = (float*)   carve(N_NODES * 4);
    unsigned* row_ptr = (unsigned*)carve((N_NODES + 1) * 4);
    unsigned* cursor  = (unsigned*)carve(N_NODES * 4);
    unsigned* bsum    = (unsigned*)carve(64 * 4);
    unsigned* gmax    = (unsigned*)carve(N_GRAPHS * 128 * 4);
    unsigned short* wph = (unsigned short*)carve(3 * 16384 * 2);
    unsigned short* wpl = (unsigned short*)carve(3 * 16384 * 2);
    int*      csr_src = (int*)     carve((size_t)N_EDGES * 4);
    char*     reg1    = carve((size_t)N_NODES * HIDDEN * 4);   // region 1 (25.6 MB)
    char*     reg2    = carve((size_t)N_NODES * HIDDEN * 4);   // region 2 (25.6 MB)
    unsigned* incl    = (unsigned*)csr_src;  // alias: dead before fill_csr runs

    // region lifetimes:
    //   reg1: xp (packed x) -> bufB (gather0 f32 out) -> bufB2 (GEMM2 f32 out)
    //   reg2: bufA (GEMM1 f32 out) -> bufAp (gather1 packed out) -> bufCp (masked packed out)
    unsigned* xp    = (unsigned*)reg1;
    float*    bufB  = (float*)reg1;
    float*    bufB2 = (float*)reg1;
    float*    bufA  = (float*)reg2;
    unsigned* bufAp = (unsigned*)reg2;
    unsigned* bufCp = (unsigned*)reg2;

    const int NB_SCAN = (N_NODES + 1023) / 1024;  // 49

    // ---- build dinv + CSR + W-prep ----
    hipMemsetAsync(deg, 0, N_NODES * sizeof(unsigned), stream);
    count_deg_kernel<<<(N_EDGES + 255) / 256, 256, 0, stream>>>(e_dst, deg);
    dinv_kernel<<<(N_NODES + 255) / 256, 256, 0, stream>>>(deg, dinv);
    scan_block_kernel<<<NB_SCAN, 1024, 0, stream>>>(deg, incl, bsum);
    scan_bsum_kernel<<<1, 64, 0, stream>>>(bsum, NB_SCAN);
    scan_finalize_kernel<<<(N_NODES + 256) / 256, 256, 0, stream>>>(incl, bsum, row_ptr, cursor);
    fill_csr_kernel<<<(N_EDGES + 255) / 256, 256, 0, stream>>>(e_src, e_dst, cursor, csr_src);
    gmax_init_kernel<<<(N_GRAPHS * 128 + 255) / 256, 256, 0, stream>>>(gmax);
    wprep_kernel<<<(3 * 16384 + 255) / 256, 256, 0, stream>>>(conv_w, wph, wpl);
    xpack_kernel<<<(N_NODES * HIDDEN + 255) / 256, 256, 0, stream>>>(x, xp, N_NODES * HIDDEN);

    const int GEMM_FULL = (N_NODES + 127) / 128;   // 391 blocks of 512 threads
    const int GEMM_MASK = (N_MASKED + 127) / 128;  // 196
    const int GA_FULL = (N_NODES * 2 * 64 + 255) / 256;
    const int GA_MASK = (N_MASKED * 2 * 64 + 255) / 256;
    const size_t LDS_BYTES = 131072;

    // L1: bufA = dinv*(x@W1)
    mfma_gemm_kernel<0><<<GEMM_FULL, 512, LDS_BYTES, stream>>>(xp, wph, wpl, dinv, nullptr,
                                                               nullptr, nullptr, bufA, N_NODES);
    // bufB = dinv*ELU(dinv*Agg(bufA) + b1)
    gather_kernel<0><<<GA_FULL, 256, 0, stream>>>(bufA, row_ptr, csr_src, dinv,
                                                  conv_b, bufB, nullptr, nullptr, N_NODES);
    // L2 gather-first: bufAp = pack(Agg(bufB))
    gather_kernel<1><<<GA_FULL, 256, 0, stream>>>(bufB, row_ptr, csr_src, dinv,
                                                  nullptr, nullptr, bufAp, nullptr, N_NODES);
    // bufB2 = dinv*ELU(bufAp@W2 + b2)
    mfma_gemm_kernel<1><<<GEMM_FULL, 512, LDS_BYTES, stream>>>(bufAp, wph + 16384, wpl + 16384,
                                                               dinv, conv_b + HIDDEN, nullptr,
                                                               nullptr, bufB2, N_NODES);
    // L3 gather-first masked: bufCp = pack(Agg_mask(bufB2))
    gather_kernel<1><<<GA_MASK, 256, 0, stream>>>(bufB2, row_ptr, csr_src, dinv,
                                                  nullptr, nullptr, bufCp, mask, N_MASKED);
    // pool(ELU(bufCp@W3 + b3)) via atomicMax
    mfma_gemm_kernel<2><<<GEMM_MASK, 512, LDS_BYTES, stream>>>(bufCp, wph + 32768, wpl + 32768,
                                                               nullptr, conv_b + 2 * HIDDEN,
                                                               batch, gmax, nullptr, N_MASKED);

    pool_finish_kernel<<<N_GRAPHS, HIDDEN, 0, stream>>>(gmax, lt1_w, lt1_b, out);
}